// Round 10
// baseline (58.038 us; speedup 1.0000x reference)
//
#include <hip/hip_runtime.h>
#include <hip/hip_bf16.h>

// LS2T iterated sums (ORDER=3): B=64, T=4096, D=128, F=64, C=6.
// m_c(t,f) = seq[b,t,:]·kernel[c,:,f] + bias[c,f]
// Y1 = sum m0; Y2 = sum m2*cumx(m1); Y3 = sum m5*cumx(m4*cumx(m3))
//
// Round 10: R6 data path, reshaped concurrency. 256-thr blocks = 4 waves
// (2 f-waves x 2 cg-waves) -> 4-wave barrier domain, 1-wave/SIMD occupancy
// granularity, 4 blocks/CU at <=128 regs. Each 512-t span is covered by two
// f-half blocks, paired onto the same XCD by a chunked bid swizzle so the
// A-tile re-read dedups in L2/L3. Same verified swizzle pair, depth-3
// register prefetch, ring-4 LDS, no-drain barriers, lane-local scan chains.

#define B_ 64
#define T_ 4096
#define D_ 128
#define F_ 64
#define TB 512             // t per span
#define TGROUPS (T_ / TB)  // 8
#define CHT 16             // t per chunk
#define NITER (TB / CHT)   // 32
#define TPB 256
#define RING 4
#define NBLK (TGROUPS * 2 * B_)   // 1024

typedef __attribute__((ext_vector_type(8))) short short8v;
typedef __attribute__((ext_vector_type(4))) float f32x4;

__device__ __forceinline__ unsigned short bfb(float x) {
    __hip_bfloat16 h = __float2bfloat16(x);   // RNE
    unsigned short u;
    __builtin_memcpy(&u, &h, 2);
    return u;
}

// barrier WITHOUT vmcnt drain: waits only LDS ops, keeps global loads in flight
#define BAR() asm volatile("s_waitcnt lgkmcnt(0)\n\ts_barrier" ::: "memory")

__global__ __launch_bounds__(TPB, 4)
void ls2t_kernel(const float* __restrict__ seq,
                 const float* __restrict__ kern,
                 const float* __restrict__ bias,
                 float* __restrict__ ws)
{
    __shared__ unsigned short slds[RING][CHT * D_];   // 4 x 4 KB bf16

    const int tid = threadIdx.x;
    // XCD-chunked swizzle: consecutive logical blocks (span fh-pairs) land on
    // the same XCD so the duplicated A-read dedups in that XCD's L2.
    const int bid     = blockIdx.x + 16 * blockIdx.y;          // 0..1023
    const int logical = (bid & 7) * (NBLK / 8) + (bid >> 3);
    const int b   = logical >> 4;
    const int rr  = logical & 15;
    const int tg  = rr >> 1;       // span
    const int fh  = rr & 1;        // f-half

    const int lane = tid & 63;
    const int w    = tid >> 6;     // 0..3
    const int cg   = w >> 1;       // 0 -> c0..2, 1 -> c3..5
    const int wv2  = w & 1;        // f-quarter within half
    const int fr   = lane & 15;
    const int lg   = lane >> 4;
    const int f    = fh * 32 + wv2 * 16 + fr;

    // ---- B fragments in registers (mfma B: col=lane&15=f, k=(lane>>4)*8+j)
    short8v bfrag[3][4];
    float bc[3];
    #pragma unroll
    for (int cc = 0; cc < 3; ++cc) {
        const int c = cg * 3 + cc;
        bc[cc] = bias[c * F_ + f];
        #pragma unroll
        for (int ks = 0; ks < 4; ++ks) {
            const float* kp = kern + ((size_t)c * D_ + ks * 32 + lg * 8) * F_ + f;
            short8v bf;
            #pragma unroll
            for (int j = 0; j < 8; ++j) bf[j] = (short)bfb(kp[(size_t)j * F_]);
            bfrag[cc][ks] = bf;
        }
    }

    const float* sbase = seq + ((size_t)b * T_ + (size_t)tg * TB) * D_;

    // staging (R6 map, 2 units/thread): unit u = k*TPB+tid -> row = u>>5,
    // float4-index c4 = u&31. Chunk row r holds t_local = (r>>2)*128+i*4+(r&3)
    // (lane-group lg owns contiguous t-stripe [lg*128,+128) over 32 chunks).
    // LDS 16B unit j of row r stores global d-block (j ^ (r&7)).
    const float* gp[2];
    int woff[2];
    #pragma unroll
    for (int k = 0; k < 2; ++k) {
        const int u  = k * TPB + tid;
        const int sr = u >> 5, c4 = u & 31;
        gp[k]   = sbase + ((size_t)((sr >> 2) * 128 + (sr & 3))) * D_ + c4 * 4;
        woff[k] = sr * D_ + 8 * ((c4 >> 1) ^ (sr & 7)) + 4 * (c4 & 1);
    }

    struct VSet { float4 a, b; };
    auto issue = [&](int i, VSet& vs) {
        vs.a = *reinterpret_cast<const float4*>(gp[0] + (size_t)i * 4 * D_);
        vs.b = *reinterpret_cast<const float4*>(gp[1] + (size_t)i * 4 * D_);
    };
    auto wst = [&](int bufi, const VSet& vs) {
        unsigned short* L = &slds[bufi][0];
        uint2 pa, pb;
        pa.x = __builtin_amdgcn_perm(__float_as_uint(vs.a.y),
                                     __float_as_uint(vs.a.x), 0x07060302u);
        pa.y = __builtin_amdgcn_perm(__float_as_uint(vs.a.w),
                                     __float_as_uint(vs.a.z), 0x07060302u);
        pb.x = __builtin_amdgcn_perm(__float_as_uint(vs.b.y),
                                     __float_as_uint(vs.b.x), 0x07060302u);
        pb.y = __builtin_amdgcn_perm(__float_as_uint(vs.b.w),
                                     __float_as_uint(vs.b.z), 0x07060302u);
        *reinterpret_cast<uint2*>(&L[woff[0]]) = pa;
        *reinterpret_cast<uint2*>(&L[woff[1]]) = pb;
    };

    // scan states (only this cg's half is live per wave)
    float a0 = 0.f, s1 = 0.f, s2 = 0.f, q2 = 0.f;
    float su = 0.f, sv = 0.f, sw = 0.f, qvu = 0.f, qwv = 0.f, qwvu = 0.f;

    auto compute = [&](int bufi) {
        f32x4 acc[3];
        #pragma unroll
        for (int cc = 0; cc < 3; ++cc)
            acc[cc] = (f32x4){bc[cc], bc[cc], bc[cc], bc[cc]};

        #pragma unroll
        for (int ks = 0; ks < 4; ++ks) {
            const int m0i = ks * 4 + lg;
            short8v a = *reinterpret_cast<const short8v*>(
                &slds[bufi][fr * D_ + 8 * (m0i ^ (fr & 7))]);
            #pragma unroll
            for (int cc = 0; cc < 3; ++cc)
                acc[cc] = __builtin_amdgcn_mfma_f32_16x16x32_bf16(
                    a, bfrag[cc][ks], acc[cc], 0, 0, 0);
        }

        // lane owns t = tg*512 + lg*128 + i*4 + r  -> chain in-lane
        if (cg == 0) {
            #pragma unroll
            for (int r = 0; r < 4; ++r) {
                float m0 = acc[0][r], m1 = acc[1][r], m2 = acc[2][r];
                a0 += m0;
                q2  = fmaf(m2, s1, q2);   // s1 = exclusive cumsum(m1)
                s2 += m2;
                s1 += m1;
            }
        } else {
            #pragma unroll
            for (int r = 0; r < 4; ++r) {
                float m3 = acc[0][r], m4 = acc[1][r], m5 = acc[2][r];
                qwvu = fmaf(m5, qvu, qwvu);
                qwv  = fmaf(m5, sv, qwv);
                sw  += m5;
                qvu  = fmaf(m4, su, qvu);
                sv  += m4;
                su  += m3;
            }
        }
    };

    // ---- pipeline: depth-3 register prefetch, ring-4 LDS, 1 barrier/iter ----
    VSet v0, v1, v2, v3;
    issue(0, v0); issue(1, v1); issue(2, v2); issue(3, v3);
    wst(0, v0);
    BAR();

    #pragma unroll 1
    for (int g = 0; g + 4 < NITER; g += 4) {
        issue(g + 4, v0);
        wst(1, v1);            // chunk g+1 (loaded 3 iters ago)
        BAR();
        compute(0);

        issue(g + 5, v1);
        wst(2, v2);
        BAR();
        compute(1);

        issue(g + 6, v2);
        wst(3, v3);
        BAR();
        compute(2);

        issue(g + 7, v3);
        wst(0, v0);            // chunk g+4
        BAR();
        compute(3);
    }
    // epilogue: chunks 28..31 (v0..v3 hold them; buf0 already has 28)
    wst(1, v1); BAR(); compute(0);
    wst(2, v2); BAR(); compute(1);
    wst(3, v3); BAR(); compute(2);
    compute(3);

    // ---- merge the 4 lane-group stripes (time order: lg ascending) ----
    if (cg == 0) {
        #pragma unroll
        for (int m = 16; m <= 32; m <<= 1) {
            float oa0 = __shfl_xor(a0, m), os1 = __shfl_xor(s1, m);
            float os2 = __shfl_xor(s2, m), oq2 = __shfl_xor(q2, m);
            bool up = (lane & m) != 0;
            float Aa0 = up ? oa0 : a0, As1 = up ? os1 : s1;
            float As2 = up ? os2 : s2, Aq2 = up ? oq2 : q2;
            float Ba0 = up ? a0 : oa0, Bs1 = up ? s1 : os1;
            float Bs2 = up ? s2 : os2, Bq2 = up ? q2 : oq2;
            a0 = Aa0 + Ba0;
            q2 = Aq2 + Bq2 + As1 * Bs2;
            s1 = As1 + Bs1;
            s2 = As2 + Bs2;
        }
        if (lg == 0) {
            float* wp = ws + (((size_t)b * TGROUPS + tg) * F_ + f) * 10;
            wp[0] = a0; wp[1] = s1; wp[2] = s2; wp[3] = q2;
        }
    } else {
        #pragma unroll
        for (int m = 16; m <= 32; m <<= 1) {
            float osu = __shfl_xor(su, m),  osv = __shfl_xor(sv, m);
            float osw = __shfl_xor(sw, m),  oqvu = __shfl_xor(qvu, m);
            float oqwv = __shfl_xor(qwv, m), oqwvu = __shfl_xor(qwvu, m);
            bool up = (lane & m) != 0;
            float Asu = up ? osu : su,   Asv = up ? osv : sv;
            float Asw = up ? osw : sw,   Aqvu = up ? oqvu : qvu;
            float Aqwv = up ? oqwv : qwv, Aqwvu = up ? oqwvu : qwvu;
            float Bsu = up ? su : osu,   Bsv = up ? sv : osv;
            float Bsw = up ? sw : osw,   Bqvu = up ? qvu : oqvu;
            float Bqwv = up ? qwv : oqwv, Bqwvu = up ? qwvu : oqwvu;
            qwvu = Aqwvu + Bqwvu + Aqvu * Bsw + Asu * Bqwv;
            qwv  = Aqwv + Bqwv + Asv * Bsw;
            qvu  = Aqvu + Bqvu + Asu * Bsv;
            su = Asu + Bsu;
            sv = Asv + Bsv;
            sw = Asw + Bsw;
        }
        if (lg == 0) {
            float* wp = ws + (((size_t)b * TGROUPS + tg) * F_ + f) * 10;
            wp[4] = su; wp[5] = sv; wp[6] = sw;
            wp[7] = qvu; wp[8] = qwv; wp[9] = qwvu;
        }
    }
}

struct St { float a0, s1, s2, q2, su, sv, sw, qvu, qwv, qwvu; };

__device__ __forceinline__ St mergeSt(const St& A, const St& B) {
    St r;
    r.a0   = A.a0 + B.a0;
    r.q2   = A.q2 + B.q2 + A.s1 * B.s2;
    r.s1   = A.s1 + B.s1;
    r.s2   = A.s2 + B.s2;
    r.qwvu = A.qwvu + B.qwvu + A.qvu * B.sw + A.su * B.qwv;
    r.qwv  = A.qwv + B.qwv + A.sv * B.sw;
    r.qvu  = A.qvu + B.qvu + A.su * B.sv;
    r.su   = A.su + B.su;
    r.sv   = A.sv + B.sv;
    r.sw   = A.sw + B.sw;
    return r;
}

__global__ __launch_bounds__(64)
void ls2t_fold_kernel(const float* __restrict__ ws, float* __restrict__ out)
{
    const int b = blockIdx.x;
    const int f = threadIdx.x;
    St A = {0, 0, 0, 0, 0, 0, 0, 0, 0, 0};
    #pragma unroll
    for (int g = 0; g < TGROUPS; ++g) {
        const float* rp = ws + (((size_t)b * TGROUPS + g) * F_ + f) * 10;
        St r = {rp[0], rp[1], rp[2], rp[3], rp[4],
                rp[5], rp[6], rp[7], rp[8], rp[9]};
        A = mergeSt(A, r);
    }
    float* op = out + ((size_t)b * F_ + f) * 3;
    op[0] = A.a0;
    op[1] = A.q2;
    op[2] = A.qwvu;
}

extern "C" void kernel_launch(void* const* d_in, const int* in_sizes, int n_in,
                              void* d_out, int out_size, void* d_ws, size_t ws_size,
                              hipStream_t stream) {
    const float* seq  = (const float*)d_in[0];
    const float* kern = (const float*)d_in[1];
    const float* bias = (const float*)d_in[2];
    float* out = (float*)d_out;
    float* ws  = (float*)d_ws;   // B_*TGROUPS*F_*10*4 = 1.31 MB

    dim3 g1(TGROUPS * 2, B_);    // 1024 blocks x 256 thr
    ls2t_kernel<<<g1, TPB, 0, stream>>>(seq, kern, bias, ws);
    ls2t_fold_kernel<<<B_, F_, 0, stream>>>(ws, out);
}

// Round 11
// 49.115 us; speedup vs baseline: 1.1817x; 1.1817x over previous
//
#include <hip/hip_runtime.h>
#include <hip/hip_bf16.h>

// LS2T iterated sums (ORDER=3): B=64, T=4096, D=128, F=64, C=6.
// m_c(t,f) = seq[b,t,:]·kernel[c,:,f] + bias[c,f]
// Y1 = sum m0; Y2 = sum m2*cumx(m1); Y3 = sum m5*cumx(m4*cumx(m3))
//
// Round 11: R6 data path; WIDER PHASES. Two 16-t chunks per barrier phase
// (16 barriers/block instead of 32, 2x per-phase ILP: 8 ds_read_b128 +
// 24 MFMA + 2 indep acc sets). Ring-8 LDS (buf j = chunk j%8, 32 KB),
// 8 static rotating float4 prefetch regs (depth = 2 phases ~ 1500 cyc).
// cg-split waves (cg0: c0..2 -> Y1,Y2; cg1: c3..5 -> Y3), B-frags in
// AGPRs, verified zero-conflict swizzle, no-drain barriers, lane-local scan.

#define B_ 64
#define T_ 4096
#define D_ 128
#define F_ 64
#define TB 512             // t per block
#define TGROUPS (T_ / TB)  // 8
#define CHT 16             // t per chunk
#define NITER (TB / CHT)   // 32 chunks = 16 phases
#define TPB 512
#define RING 8

typedef __attribute__((ext_vector_type(8))) short short8v;
typedef __attribute__((ext_vector_type(4))) float f32x4;
typedef __attribute__((ext_vector_type(4))) unsigned short ushort4v;

__device__ __forceinline__ unsigned short bfb(float x) {
    __hip_bfloat16 h = __float2bfloat16(x);   // RNE
    unsigned short u;
    __builtin_memcpy(&u, &h, 2);
    return u;
}

// barrier WITHOUT vmcnt drain: waits only LDS ops, keeps global loads in flight
#define BAR() asm volatile("s_waitcnt lgkmcnt(0)\n\ts_barrier" ::: "memory")

__global__ __launch_bounds__(TPB, 2)
void ls2t_kernel(const float* __restrict__ seq,
                 const float* __restrict__ kern,
                 const float* __restrict__ bias,
                 float* __restrict__ ws)
{
    __shared__ unsigned short slds[RING][CHT * D_];   // 8 x 4 KB bf16

    const int tid  = threadIdx.x;
    const int tg   = blockIdx.x;
    const int b    = blockIdx.y;
    const int lane = tid & 63;
    const int w    = tid >> 6;
    const int cg   = w >> 2;       // 0 -> c0..2, 1 -> c3..5
    const int wv   = w & 3;        // f-range of this wave
    const int fr   = lane & 15;
    const int lg   = lane >> 4;
    const int f    = wv * 16 + fr;

    // ---- B fragments in registers (mfma B: col=lane&15=f, k=(lane>>4)*8+j)
    short8v bfrag[3][4];
    float bc[3];
    #pragma unroll
    for (int cc = 0; cc < 3; ++cc) {
        const int c = cg * 3 + cc;
        bc[cc] = bias[c * F_ + f];
        #pragma unroll
        for (int ks = 0; ks < 4; ++ks) {
            const float* kp = kern + ((size_t)c * D_ + ks * 32 + lg * 8) * F_ + f;
            short8v bf;
            #pragma unroll
            for (int j = 0; j < 8; ++j) bf[j] = (short)bfb(kp[(size_t)j * F_]);
            bfrag[cc][ks] = bf;
        }
    }

    const float* sbase = seq + ((size_t)b * T_ + (size_t)tg * TB) * D_;

    // staging (R6 map): thread -> (row srow 0..15, float4-index c4 0..31).
    // chunk row r holds t_local = (r>>2)*128 + i*4 + (r&3): lane-group lg owns
    // contiguous t-stripe [lg*128, +128) across the 32 chunks.
    // LDS 16B block jb of row r contains global d-block (jb ^ (r&7)).
    const int srow = tid >> 5;
    const int c4   = tid & 31;
    const float* g0 = sbase + ((size_t)((srow >> 2) * 128 + (srow & 3))) * D_ + c4 * 4;
    const int woff = srow * D_ + 8 * ((c4 >> 1) ^ (srow & 7)) + 4 * (c4 & 1);  // shorts

    #define LD(i) (*reinterpret_cast<const float4*>(g0 + (size_t)(i) * 4 * D_))

    auto wst = [&](int bufi, const float4& v) {
        ushort4v u;
        u[0] = bfb(v.x); u[1] = bfb(v.y); u[2] = bfb(v.z); u[3] = bfb(v.w);
        *reinterpret_cast<ushort4v*>(&slds[bufi][woff]) = u;
    };

    // scan states (only this cg's half is live per wave)
    float a0 = 0.f, s1 = 0.f, s2 = 0.f, q2 = 0.f;
    float su = 0.f, sv = 0.f, sw = 0.f, qvu = 0.f, qwv = 0.f, qwvu = 0.f;

    auto compute = [&](int bufi) {
        f32x4 acc[3];
        #pragma unroll
        for (int cc = 0; cc < 3; ++cc)
            acc[cc] = (f32x4){bc[cc], bc[cc], bc[cc], bc[cc]};

        #pragma unroll
        for (int ks = 0; ks < 4; ++ks) {
            const int m0i = ks * 4 + lg;
            short8v a = *reinterpret_cast<const short8v*>(
                &slds[bufi][fr * D_ + 8 * (m0i ^ (fr & 7))]);
            #pragma unroll
            for (int cc = 0; cc < 3; ++cc)
                acc[cc] = __builtin_amdgcn_mfma_f32_16x16x32_bf16(
                    a, bfrag[cc][ks], acc[cc], 0, 0, 0);
        }

        // lane owns t = tg*512 + lg*128 + i*4 + r  -> chain in-lane
        if (cg == 0) {
            #pragma unroll
            for (int r = 0; r < 4; ++r) {
                float m0 = acc[0][r], m1 = acc[1][r], m2 = acc[2][r];
                a0 += m0;
                q2  = fmaf(m2, s1, q2);   // s1 = exclusive cumsum(m1)
                s2 += m2;
                s1 += m1;
            }
        } else {
            #pragma unroll
            for (int r = 0; r < 4; ++r) {
                float m3 = acc[0][r], m4 = acc[1][r], m5 = acc[2][r];
                qwvu = fmaf(m5, qvu, qwvu);
                qwv  = fmaf(m5, sv, qwv);
                sw  += m5;
                qvu  = fmaf(m4, su, qvu);
                sv  += m4;
                su  += m3;
            }
        }
    };

    // ---- pipeline: 2 chunks per phase, ring-8 (buf j = chunk j%8),
    //      8 static prefetch reg sets (chunk j -> w[j%8]), depth 2 phases ----
    float4 w0 = LD(0), w1 = LD(1), w2 = LD(2), w3 = LD(3), w4 = LD(4), w5 = LD(5);
    float4 w6, w7;
    wst(0, w0); wst(1, w1);
    BAR();

    #pragma unroll 1
    for (int cb = 0; cb < 24; cb += 8) {
        // phase p%4==0: compute cb,cb+1
        w6 = LD(cb + 6); w7 = LD(cb + 7);
        wst(2, w2); wst(3, w3);
        BAR();
        compute(0); compute(1);
        // phase 1: compute cb+2,cb+3
        w0 = LD(cb + 8); w1 = LD(cb + 9);
        wst(4, w4); wst(5, w5);
        BAR();
        compute(2); compute(3);
        // phase 2: compute cb+4,cb+5
        w2 = LD(cb + 10); w3 = LD(cb + 11);
        wst(6, w6); wst(7, w7);
        BAR();
        compute(4); compute(5);
        // phase 3: compute cb+6,cb+7
        w4 = LD(cb + 12); w5 = LD(cb + 13);
        wst(0, w0); wst(1, w1);
        BAR();
        compute(6); compute(7);
    }
    // tail phases (chunks 24..31; w0..w7 hold 24..31 after the loop)
    w6 = LD(30); w7 = LD(31);
    wst(2, w2); wst(3, w3);        // chunks 26,27
    BAR();
    compute(0); compute(1);        // 24,25
    wst(4, w4); wst(5, w5);        // 28,29
    BAR();
    compute(2); compute(3);        // 26,27
    wst(6, w6); wst(7, w7);        // 30,31
    BAR();
    compute(4); compute(5);        // 28,29
    compute(6); compute(7);        // 30,31 (written before last BAR)

    // ---- merge the 4 lane-group stripes (time order: lg ascending) ----
    if (cg == 0) {
        #pragma unroll
        for (int m = 16; m <= 32; m <<= 1) {
            float oa0 = __shfl_xor(a0, m), os1 = __shfl_xor(s1, m);
            float os2 = __shfl_xor(s2, m), oq2 = __shfl_xor(q2, m);
            bool up = (lane & m) != 0;
            float Aa0 = up ? oa0 : a0, As1 = up ? os1 : s1;
            float As2 = up ? os2 : s2, Aq2 = up ? oq2 : q2;
            float Ba0 = up ? a0 : oa0, Bs1 = up ? s1 : os1;
            float Bs2 = up ? s2 : os2, Bq2 = up ? q2 : oq2;
            a0 = Aa0 + Ba0;
            q2 = Aq2 + Bq2 + As1 * Bs2;
            s1 = As1 + Bs1;
            s2 = As2 + Bs2;
        }
        if (lg == 0) {
            float* wp = ws + (((size_t)b * TGROUPS + tg) * F_ + f) * 10;
            wp[0] = a0; wp[1] = s1; wp[2] = s2; wp[3] = q2;
        }
    } else {
        #pragma unroll
        for (int m = 16; m <= 32; m <<= 1) {
            float osu = __shfl_xor(su, m),  osv = __shfl_xor(sv, m);
            float osw = __shfl_xor(sw, m),  oqvu = __shfl_xor(qvu, m);
            float oqwv = __shfl_xor(qwv, m), oqwvu = __shfl_xor(qwvu, m);
            bool up = (lane & m) != 0;
            float Asu = up ? osu : su,   Asv = up ? osv : sv;
            float Asw = up ? osw : sw,   Aqvu = up ? oqvu : qvu;
            float Aqwv = up ? oqwv : qwv, Aqwvu = up ? oqwvu : qwvu;
            float Bsu = up ? su : osu,   Bsv = up ? sv : osv;
            float Bsw = up ? sw : osw,   Bqvu = up ? qvu : oqvu;
            float Bqwv = up ? qwv : oqwv, Bqwvu = up ? qwvu : oqwvu;
            qwvu = Aqwvu + Bqwvu + Aqvu * Bsw + Asu * Bqwv;
            qwv  = Aqwv + Bqwv + Asv * Bsw;
            qvu  = Aqvu + Bqvu + Asu * Bsv;
            su = Asu + Bsu;
            sv = Asv + Bsv;
            sw = Asw + Bsw;
        }
        if (lg == 0) {
            float* wp = ws + (((size_t)b * TGROUPS + tg) * F_ + f) * 10;
            wp[4] = su; wp[5] = sv; wp[6] = sw;
            wp[7] = qvu; wp[8] = qwv; wp[9] = qwvu;
        }
    }
    #undef LD
}

struct St { float a0, s1, s2, q2, su, sv, sw, qvu, qwv, qwvu; };

__device__ __forceinline__ St mergeSt(const St& A, const St& B) {
    St r;
    r.a0   = A.a0 + B.a0;
    r.q2   = A.q2 + B.q2 + A.s1 * B.s2;
    r.s1   = A.s1 + B.s1;
    r.s2   = A.s2 + B.s2;
    r.qwvu = A.qwvu + B.qwvu + A.qvu * B.sw + A.su * B.qwv;
    r.qwv  = A.qwv + B.qwv + A.sv * B.sw;
    r.qvu  = A.qvu + B.qvu + A.su * B.sv;
    r.su   = A.su + B.su;
    r.sv   = A.sv + B.sv;
    r.sw   = A.sw + B.sw;
    return r;
}

__global__ __launch_bounds__(64)
void ls2t_fold_kernel(const float* __restrict__ ws, float* __restrict__ out)
{
    const int b = blockIdx.x;
    const int f = threadIdx.x;
    St A = {0, 0, 0, 0, 0, 0, 0, 0, 0, 0};
    #pragma unroll
    for (int g = 0; g < TGROUPS; ++g) {
        const float* rp = ws + (((size_t)b * TGROUPS + g) * F_ + f) * 10;
        St r = {rp[0], rp[1], rp[2], rp[3], rp[4],
                rp[5], rp[6], rp[7], rp[8], rp[9]};
        A = mergeSt(A, r);
    }
    float* op = out + ((size_t)b * F_ + f) * 3;
    op[0] = A.a0;
    op[1] = A.q2;
    op[2] = A.qwvu;
}

extern "C" void kernel_launch(void* const* d_in, const int* in_sizes, int n_in,
                              void* d_out, int out_size, void* d_ws, size_t ws_size,
                              hipStream_t stream) {
    const float* seq  = (const float*)d_in[0];
    const float* kern = (const float*)d_in[1];
    const float* bias = (const float*)d_in[2];
    float* out = (float*)d_out;
    float* ws  = (float*)d_ws;   // B_*TGROUPS*F_*10*4 = 1.31 MB

    dim3 g1(TGROUPS, B_);        // 512 blocks x 512 thr, 2 per CU
    ls2t_kernel<<<g1, TPB, 0, stream>>>(seq, kern, bias, ws);
    ls2t_fold_kernel<<<B_, F_, 0, stream>>>(ws, out);
}